// Round 9
// baseline (48.889 us; speedup 1.0000x reference)
//
#include <hip/hip_runtime.h>
#include <math.h>

// ChamferLoss: pc_src [B,3,M] f32, pc_dst [B,3,N] f32 -> scalar mean over (B,M)
// of min_n ||src_m - dst_n||.
//
// Identity: min_n d2 = |a|^2 + min_n (|b|^2 - 2 a.b).
// R8 -> R9: dst broadcast moved OFF the DS pipe. Each wave holds the
// segment's 128 dst points lane-resident (2 chunks x 64 lanes x 4 regs of
// (-2x,-2y,-2z,|b|^2)); the inner loop broadcasts point j via v_readlane
// (VALU-issued, uniform SGPR index) -> no ds_read, no lgkmcnt, single-pipe
// VALU kernel. Per 2 dst per wave: 8 readlane + 2 mov + 48 FMA + 8 min3.
// Skeleton = R3/R7 champion: SPT=8, NSEG=64, bounds(256,4), atomicMin into
// 128 KB minenc, fused ticket/fixed-point finish, memset init.

#define TPB 256

constexpr int NB = 4;
constexpr int NM = 8192;
constexpr int NN = 8192;
constexpr int NSEG = 64;                          // dst segments
constexpr int SEG = NN / NSEG;                    // 128 dst per segment
constexpr int NCH = SEG / 64;                     // 2 lane-chunks per segment
constexpr int SPT = 8;                            // src points per thread
constexpr int SRC_PER_BLOCK = TPB * SPT;          // 2048
constexpr int NPTS = NB * NM;                     // 32768
constexpr int CHUNKS = NPTS / SRC_PER_BLOCK;      // 16
constexpr int CHUNKS_PER_B = NM / SRC_PER_BLOCK;  // 4
constexpr int NBLK_C = NPTS / TPB;                // 128

// Order-preserving float<->uint encode so unsigned atomicMin == float min.
__device__ __forceinline__ unsigned enc_f32(float f) {
    unsigned u = __float_as_uint(f);
    return (u & 0x80000000u) ? ~u : (u | 0x80000000u);
}
__device__ __forceinline__ float dec_f32(unsigned u) {
    unsigned b = (u & 0x80000000u) ? (u ^ 0x80000000u) : ~u;
    return __uint_as_float(b);
}

// Broadcast lane l's value of v to all lanes (uniform l) via v_readlane.
__device__ __forceinline__ float rl(float v, int l) {
    return __uint_as_float(__builtin_amdgcn_readlane(__float_as_uint(v), l));
}

// Kernel 1: per (src-chunk, dst-segment) block. Segment's dst4 lane-resident;
// running min of (b^2 - 2 a.b) over 8 src points/thread; atomicMin out.
__global__ __launch_bounds__(TPB, 4) void minseg_kernel(const float* __restrict__ src,
                                                        const float* __restrict__ dst,
                                                        unsigned* __restrict__ minenc,
                                                        unsigned long long* __restrict__ sumfix,
                                                        unsigned* __restrict__ ticket) {
    int chunk = blockIdx.x % CHUNKS;
    int seg   = blockIdx.x / CHUNKS;
    int b  = chunk / CHUNKS_PER_B;
    int t  = threadIdx.x;
    int lane = t & 63;

    if (blockIdx.x == 0 && t == 0) { *sumfix = 0ULL; *ticket = 0u; }

    // Lane-resident dst chunks: lane l holds dst point seg*SEG + c*64 + l.
    const float* pd = dst + (size_t)b * 3 * NN;
    float X[NCH], Y[NCH], Z[NCH], W[NCH];
#pragma unroll
    for (int c = 0; c < NCH; ++c) {
        int n = seg * SEG + c * 64 + lane;
        float x = pd[n], y = pd[NN + n], z = pd[2 * NN + n];
        X[c] = -2.0f * x;
        Y[c] = -2.0f * y;
        Z[c] = -2.0f * z;
        W[c] = fmaf(x, x, fmaf(y, y, z * z));
    }

    int m0 = (chunk % CHUNKS_PER_B) * SRC_PER_BLOCK + t;
    const float* sp = src + (size_t)b * 3 * NM;

    float ax[SPT], ay[SPT], az[SPT], mn[SPT];
#pragma unroll
    for (int k = 0; k < SPT; ++k) {
        int m = m0 + k * TPB;
        ax[k] = sp[m];
        ay[k] = sp[NM + m];
        az[k] = sp[2 * NM + m];
        mn[k] = 3.4e38f;
    }

#pragma unroll
    for (int c = 0; c < NCH; ++c) {
#pragma unroll 2
        for (int jj = 0; jj < 64; jj += 2) {
            float sx0 = rl(X[c], jj),     sy0 = rl(Y[c], jj);
            float sz0 = rl(Z[c], jj),     sw0 = rl(W[c], jj);
            float sx1 = rl(X[c], jj + 1), sy1 = rl(Y[c], jj + 1);
            float sz1 = rl(Z[c], jj + 1), sw1 = rl(W[c], jj + 1);
#pragma unroll
            for (int k = 0; k < SPT; ++k) {
                float t0 = fmaf(az[k], sz0, sw0);
                t0 = fmaf(ay[k], sy0, t0);
                t0 = fmaf(ax[k], sx0, t0);
                float t1 = fmaf(az[k], sz1, sw1);
                t1 = fmaf(ay[k], sy1, t1);
                t1 = fmaf(ax[k], sx1, t1);
                mn[k] = fminf(fminf(t0, t1), mn[k]);   // -> v_min3_f32
            }
        }
    }

#pragma unroll
    for (int k = 0; k < SPT; ++k) {
        int gm = b * NM + m0 + k * TPB;
        atomicMin(&minenc[gm], enc_f32(mn[k]));        // exact, order-independent
    }
}

// Kernel 2: per src point, d = sqrt(max(a^2 + minval, 0)); block tree-sum;
// deterministic fixed-point accumulate; last block (ticket) writes scalar.
__global__ __launch_bounds__(TPB) void finish_kernel(const float* __restrict__ src,
                                                     const unsigned* __restrict__ minenc,
                                                     unsigned long long* __restrict__ sumfix,
                                                     unsigned* __restrict__ ticket,
                                                     float* __restrict__ out) {
    int gm = blockIdx.x * TPB + threadIdx.x;
    int b = gm / NM, m = gm % NM;
    const float* sp = src + (size_t)b * 3 * NM;
    float x = sp[m], y = sp[NM + m], z = sp[2 * NM + m];
    float a2 = fmaf(x, x, fmaf(y, y, z * z));
    float v = dec_f32(minenc[gm]);
    float d = sqrtf(fmaxf(a2 + v, 0.0f));

    for (int off = 32; off > 0; off >>= 1) d += __shfl_down(d, off);
    __shared__ float wsum[4];
    int lane = threadIdx.x & 63, w = threadIdx.x >> 6;
    if (lane == 0) wsum[w] = d;
    __syncthreads();

    if (threadIdx.x == 0) {
        float bs = (wsum[0] + wsum[1]) + (wsum[2] + wsum[3]);
        // Fixed-point (32.32) accumulate: integer adds are associative ->
        // deterministic regardless of block order.
        unsigned long long inc = (unsigned long long)((double)bs * 4294967296.0);
        atomicAdd(sumfix, inc);
        __threadfence();                          // sum-add before ticket-add
        unsigned tk = atomicAdd(ticket, 1u);
        if (tk == NBLK_C - 1) {
            unsigned long long tot = atomicAdd(sumfix, 0ULL);  // coherent read
            out[0] = (float)((double)tot * (1.0 / 4294967296.0) * (1.0 / NPTS));
        }
    }
}

extern "C" void kernel_launch(void* const* d_in, const int* in_sizes, int n_in,
                              void* d_out, int out_size, void* d_ws, size_t ws_size,
                              hipStream_t stream) {
    const float* src = (const float*)d_in[0];   // [B,3,M]
    const float* dst = (const float*)d_in[1];   // [B,3,N]
    float* out = (float*)d_out;

    char* ws = (char*)d_ws;
    unsigned* minenc = (unsigned*)ws;                                // 128 KB
    unsigned long long* sumfix =
        (unsigned long long*)(ws + (size_t)NPTS * 4);                // 8 B
    unsigned* ticket = (unsigned*)(ws + (size_t)NPTS * 4 + 8);       // 4 B

    hipMemsetAsync(minenc, 0xFF, (size_t)NPTS * 4, stream);          // > +inf
    minseg_kernel<<<CHUNKS * NSEG, TPB, 0, stream>>>(src, dst, minenc, sumfix, ticket);
    finish_kernel<<<NBLK_C, TPB, 0, stream>>>(src, minenc, sumfix, ticket, out);
}

// Round 10
// 36.233 us; speedup vs baseline: 1.3493x; 1.3493x over previous
//
#include <hip/hip_runtime.h>
#include <math.h>

// ChamferLoss: pc_src [B,3,M] f32, pc_dst [B,3,N] f32 -> scalar mean over (B,M)
// of min_n ||src_m - dst_n||.
//
// Identity: min_n d2 = |a|^2 + min_n (|b|^2 - 2 a.b).
// Per-dst float4 (-2bx,-2by,-2bz,|b|^2) staged in LDS; inner loop is
// 3 FMA + half v_min3 per pair (3.5 VALU lane-ops/pair, floor ~12 us).
//
// R9 -> R10: back to the LDS-broadcast engine (readlane engine measured
// slower: 38.6us @ 73.7% VALU — more instrs/pair). Two changes vs the R3
// champion: (1) software-pipelined LDS reads — groups of 8 ds_read_b128
// issued back-to-back, then 8 dst of compute; first FMA waits lgkmcnt(6),
// later reads' latency hides under 224 VALU cycles (the R3 limiter was
// DS queue delay ~ half the kernel time); (2) NSEG 64->128 -> grid 2048 =
// 8 blocks/CU; VGPR ~76 fits bounds(256,4) cap 128 with no spill (R5's
// regression was the forced 64-cap, not occupancy itself).

#define TPB 256

constexpr int NB = 4;
constexpr int NM = 8192;
constexpr int NN = 8192;
constexpr int NSEG = 128;                         // dst segments
constexpr int SEG = NN / NSEG;                    // 64 dst per segment
constexpr int SPT = 8;                            // src points per thread
constexpr int SRC_PER_BLOCK = TPB * SPT;          // 2048
constexpr int NPTS = NB * NM;                     // 32768
constexpr int CHUNKS = NPTS / SRC_PER_BLOCK;      // 16
constexpr int CHUNKS_PER_B = NM / SRC_PER_BLOCK;  // 4
constexpr int NBLK_C = NPTS / TPB;                // 128

// Order-preserving float<->uint encode so unsigned atomicMin == float min.
__device__ __forceinline__ unsigned enc_f32(float f) {
    unsigned u = __float_as_uint(f);
    return (u & 0x80000000u) ? ~u : (u | 0x80000000u);
}
__device__ __forceinline__ float dec_f32(unsigned u) {
    unsigned b = (u & 0x80000000u) ? (u ^ 0x80000000u) : ~u;
    return __uint_as_float(b);
}

// Kernel 1: per (src-chunk, dst-segment) block. Segment dst4 in LDS;
// pipelined 8-wide LDS read groups; running min over 8 src points/thread.
__global__ __launch_bounds__(TPB, 4) void minseg_kernel(const float* __restrict__ src,
                                                        const float* __restrict__ dst,
                                                        unsigned* __restrict__ minenc,
                                                        unsigned long long* __restrict__ sumfix,
                                                        unsigned* __restrict__ ticket) {
    __shared__ float4 sdst[SEG];                  // 1 KB

    int chunk = blockIdx.x % CHUNKS;
    int seg   = blockIdx.x / CHUNKS;
    int b  = chunk / CHUNKS_PER_B;
    int t  = threadIdx.x;

    if (blockIdx.x == 0 && t == 0) { *sumfix = 0ULL; *ticket = 0u; }

    if (t < SEG) {
        int n = seg * SEG + t;
        const float* p = dst + (size_t)b * 3 * NN;
        float x = p[n], y = p[NN + n], z = p[2 * NN + n];
        sdst[t] = make_float4(-2.0f * x, -2.0f * y, -2.0f * z,
                              fmaf(x, x, fmaf(y, y, z * z)));
    }

    int m0 = (chunk % CHUNKS_PER_B) * SRC_PER_BLOCK + t;
    const float* sp = src + (size_t)b * 3 * NM;

    float ax[SPT], ay[SPT], az[SPT], mn[SPT];
#pragma unroll
    for (int k = 0; k < SPT; ++k) {
        int m = m0 + k * TPB;
        ax[k] = sp[m];
        ay[k] = sp[NM + m];
        az[k] = sp[2 * NM + m];
        mn[k] = 3.4e38f;
    }
    __syncthreads();

#pragma unroll 1
    for (int jg = 0; jg < SEG; jg += 8) {
        float4 d[8];                              // load phase: 8 back-to-back
#pragma unroll
        for (int u = 0; u < 8; ++u) d[u] = sdst[jg + u];
#pragma unroll
        for (int u = 0; u < 8; u += 2) {          // compute phase
            float4 d0 = d[u], d1 = d[u + 1];
#pragma unroll
            for (int k = 0; k < SPT; ++k) {
                float t0 = fmaf(az[k], d0.z, d0.w);
                t0 = fmaf(ay[k], d0.y, t0);
                t0 = fmaf(ax[k], d0.x, t0);
                float t1 = fmaf(az[k], d1.z, d1.w);
                t1 = fmaf(ay[k], d1.y, t1);
                t1 = fmaf(ax[k], d1.x, t1);
                mn[k] = fminf(fminf(t0, t1), mn[k]);   // -> v_min3_f32
            }
        }
    }

#pragma unroll
    for (int k = 0; k < SPT; ++k) {
        int gm = b * NM + m0 + k * TPB;
        atomicMin(&minenc[gm], enc_f32(mn[k]));   // exact, order-independent
    }
}

// Kernel 2: per src point, d = sqrt(max(a^2 + minval, 0)); block tree-sum;
// deterministic fixed-point accumulate; last block (ticket) writes scalar.
__global__ __launch_bounds__(TPB) void finish_kernel(const float* __restrict__ src,
                                                     const unsigned* __restrict__ minenc,
                                                     unsigned long long* __restrict__ sumfix,
                                                     unsigned* __restrict__ ticket,
                                                     float* __restrict__ out) {
    int gm = blockIdx.x * TPB + threadIdx.x;
    int b = gm / NM, m = gm % NM;
    const float* sp = src + (size_t)b * 3 * NM;
    float x = sp[m], y = sp[NM + m], z = sp[2 * NM + m];
    float a2 = fmaf(x, x, fmaf(y, y, z * z));
    float v = dec_f32(minenc[gm]);
    float d = sqrtf(fmaxf(a2 + v, 0.0f));

    for (int off = 32; off > 0; off >>= 1) d += __shfl_down(d, off);
    __shared__ float wsum[4];
    int lane = threadIdx.x & 63, w = threadIdx.x >> 6;
    if (lane == 0) wsum[w] = d;
    __syncthreads();

    if (threadIdx.x == 0) {
        float bs = (wsum[0] + wsum[1]) + (wsum[2] + wsum[3]);
        // Fixed-point (32.32) accumulate: integer adds are associative ->
        // deterministic regardless of block order.
        unsigned long long inc = (unsigned long long)((double)bs * 4294967296.0);
        atomicAdd(sumfix, inc);
        __threadfence();                          // sum-add before ticket-add
        unsigned tk = atomicAdd(ticket, 1u);
        if (tk == NBLK_C - 1) {
            unsigned long long tot = atomicAdd(sumfix, 0ULL);  // coherent read
            out[0] = (float)((double)tot * (1.0 / 4294967296.0) * (1.0 / NPTS));
        }
    }
}

extern "C" void kernel_launch(void* const* d_in, const int* in_sizes, int n_in,
                              void* d_out, int out_size, void* d_ws, size_t ws_size,
                              hipStream_t stream) {
    const float* src = (const float*)d_in[0];   // [B,3,M]
    const float* dst = (const float*)d_in[1];   // [B,3,N]
    float* out = (float*)d_out;

    char* ws = (char*)d_ws;
    unsigned* minenc = (unsigned*)ws;                                // 128 KB
    unsigned long long* sumfix =
        (unsigned long long*)(ws + (size_t)NPTS * 4);                // 8 B
    unsigned* ticket = (unsigned*)(ws + (size_t)NPTS * 4 + 8);       // 4 B

    hipMemsetAsync(minenc, 0xFF, (size_t)NPTS * 4, stream);          // > +inf
    minseg_kernel<<<CHUNKS * NSEG, TPB, 0, stream>>>(src, dst, minenc, sumfix, ticket);
    finish_kernel<<<NBLK_C, TPB, 0, stream>>>(src, minenc, sumfix, ticket, out);
}

// Round 11
// 31.136 us; speedup vs baseline: 1.5702x; 1.1637x over previous
//
#include <hip/hip_runtime.h>
#include <math.h>

// ChamferLoss: pc_src [B,3,M] f32, pc_dst [B,3,N] f32 -> scalar mean over (B,M)
// of min_n ||src_m - dst_n||.
//
// R10 -> R11: MFMA engine. d2p(n,m) = |d_n|^2 - 2 s_m . d_n computed as ONE
// K-column of v_mfma_f32_32x32x16_f16 (A=dst rows, B=src cols), using 11 of
// 16 K-slots with split-f16 precision (per coord: uh*sh, uh*sl, ul*sh with
// u=-2d; plus (wh,wl)*1 for |d|^2; dropped ul*sl ~ 2^-22 rel -> d2 err ~3e-5).
// Fragments precomputed packed (32 B/point) by prep so minseg per 32x32 tile
// is: 1 dwordx4 load + 1 MFMA + 8 v_min3 (row-min tree) . Min over all n via
// per-wave acc + shfl_xor(32) + atomicMin(order-encoded). finish adds |s|^2,
// sqrt, ticket + fixed-point sum (unchanged champion epilogue).

#define TPB 256

constexpr int NB = 4;
constexpr int NM = 8192;
constexpr int NN = 8192;
constexpr int NPTS = NB * NM;                     // 32768 src (= dst) points
constexpr int NSEG = 8;                           // dst segments of 1024
constexpr int DSEG = NN / NSEG;                   // 1024 dst per segment
constexpr int TILES = DSEG / 32;                  // 32 MFMA tiles per wave
constexpr int NBLK_C = NPTS / TPB;                // 128 finish blocks

typedef _Float16 half8 __attribute__((ext_vector_type(8)));
typedef float f32x16 __attribute__((ext_vector_type(16)));

// Order-preserving float<->uint encode so unsigned atomicMin == float min.
__device__ __forceinline__ unsigned enc_f32(float f) {
    unsigned u = __float_as_uint(f);
    return (u & 0x80000000u) ? ~u : (u | 0x80000000u);
}
__device__ __forceinline__ float dec_f32(unsigned u) {
    unsigned b = (u & 0x80000000u) ? (u ^ 0x80000000u) : ~u;
    return __uint_as_float(b);
}
__device__ __forceinline__ float min3(float a, float b, float c) {
    return fminf(fminf(a, b), c);                 // -> v_min3_f32
}

// Kernel 0: pack per-point MFMA fragments (16 f16 = 32 B each side), init
// minenc / sum cells.
// A-side (dst d; u=-2d, w=|d|^2):  [uhx uhx ulx uhy uhy uly uhz uhz | ulz wh wl 0 0 0 0 0]
// B-side (src s):                  [shx slx shx shy sly shy shz slz | shz  1  1 0 0 0 0 0]
__global__ __launch_bounds__(TPB) void prep_kernel(const float* __restrict__ src,
                                                   const float* __restrict__ dst,
                                                   char* __restrict__ dstfrag,
                                                   char* __restrict__ srcfrag,
                                                   unsigned* __restrict__ minenc,
                                                   unsigned long long* __restrict__ sumfix,
                                                   unsigned* __restrict__ ticket) {
    int idx = blockIdx.x * TPB + threadIdx.x;     // 0..NPTS
    if (idx == 0) { *sumfix = 0ULL; *ticket = 0u; }
    minenc[idx] = 0xFFFFFFFFu;                    // encodes > +inf
    int b = idx >> 13, n = idx & (NN - 1);

    {   // dst side
        const float* p = dst + (size_t)b * 3 * NN;
        float x = p[n], y = p[NN + n], z = p[2 * NN + n];
        float ux = -2.0f * x, uy = -2.0f * y, uz = -2.0f * z;
        float w = fmaf(x, x, fmaf(y, y, z * z));
        _Float16 uhx = (_Float16)ux; _Float16 ulx = (_Float16)(ux - (float)uhx);
        _Float16 uhy = (_Float16)uy; _Float16 uly = (_Float16)(uy - (float)uhy);
        _Float16 uhz = (_Float16)uz; _Float16 ulz = (_Float16)(uz - (float)uhz);
        _Float16 wh  = (_Float16)w;  _Float16 wl  = (_Float16)(w - (float)wh);
        half8 a0 = {uhx, uhx, ulx, uhy, uhy, uly, uhz, uhz};
        half8 a1 = {ulz, wh, wl, (_Float16)0.f, (_Float16)0.f,
                    (_Float16)0.f, (_Float16)0.f, (_Float16)0.f};
        *(half8*)(dstfrag + (size_t)idx * 32)      = a0;
        *(half8*)(dstfrag + (size_t)idx * 32 + 16) = a1;
    }
    {   // src side
        const float* p = src + (size_t)b * 3 * NM;
        float x = p[n], y = p[NM + n], z = p[2 * NM + n];
        _Float16 shx = (_Float16)x; _Float16 slx = (_Float16)(x - (float)shx);
        _Float16 shy = (_Float16)y; _Float16 sly = (_Float16)(y - (float)shy);
        _Float16 shz = (_Float16)z; _Float16 slz = (_Float16)(z - (float)shz);
        half8 b0 = {shx, slx, shx, shy, sly, shy, shz, slz};
        half8 b1 = {shz, (_Float16)1.f, (_Float16)1.f, (_Float16)0.f,
                    (_Float16)0.f, (_Float16)0.f, (_Float16)0.f, (_Float16)0.f};
        *(half8*)(srcfrag + (size_t)idx * 32)      = b0;
        *(half8*)(srcfrag + (size_t)idx * 32 + 16) = b1;
    }
}

// Kernel 1: per block (4 waves): 4 src-tiles x one dst-segment. Each wave:
// B-frag resident (its 32 src), loop 32 dst-tiles: load A-frag, MFMA, row-min
// tree into acc; epilogue: cross-lane-group min + atomicMin per src col.
__global__ __launch_bounds__(TPB) void minseg_kernel(const char* __restrict__ dstfrag,
                                                     const char* __restrict__ srcfrag,
                                                     unsigned* __restrict__ minenc) {
    int l = threadIdx.x & 63;
    int wv = threadIdx.x >> 6;
    int sg = blockIdx.x & (NSEG - 1);
    int rest = blockIdx.x >> 3;
    int srcgrp = rest & 63;
    int b = rest >> 6;

    int mbase = (srcgrp * 4 + wv) * 32;           // this wave's 32 src cols
    const char* bptr = srcfrag + ((size_t)(b * NM + mbase + (l & 31)) * 32)
                               + ((l >> 5) * 16);
    half8 bf = *(const half8*)bptr;

    const char* aptr = dstfrag + ((size_t)(b * NN + sg * DSEG + (l & 31)) * 32)
                               + ((l >> 5) * 16);

    const f32x16 zc = {0.f,0.f,0.f,0.f,0.f,0.f,0.f,0.f,
                       0.f,0.f,0.f,0.f,0.f,0.f,0.f,0.f};
    float acc = 3.4e38f;
    half8 af = *(const half8*)aptr;
#pragma unroll 2
    for (int j = 0; j < TILES; ++j) {
        half8 nx = (j < TILES - 1) ? *(const half8*)(aptr + (size_t)(j + 1) * 1024)
                                   : af;          // prefetch next tile
        f32x16 c = __builtin_amdgcn_mfma_f32_32x32x16_f16(af, bf, zc, 0, 0, 0);
        float v0 = min3(c[0],  c[1],  c[2]);
        float v1 = min3(c[3],  c[4],  c[5]);
        float v2 = min3(c[6],  c[7],  c[8]);
        float v3 = min3(c[9],  c[10], c[11]);
        float v4 = min3(c[12], c[13], c[14]);
        float w0 = min3(v0, v1, c[15]);
        float w1 = min3(v2, v3, v4);
        acc = min3(acc, w0, w1);
        af = nx;
    }

    float o = __shfl_xor(acc, 32);                // merge the two lane-groups
    acc = fminf(acc, o);
    if (l < 32)
        atomicMin(&minenc[b * NM + mbase + l], enc_f32(acc));  // exact min
}

// Kernel 2: per src point, d = sqrt(max(|s|^2 + minval, 0)); block tree-sum;
// deterministic fixed-point accumulate; last block (ticket) writes scalar.
__global__ __launch_bounds__(TPB) void finish_kernel(const float* __restrict__ src,
                                                     const unsigned* __restrict__ minenc,
                                                     unsigned long long* __restrict__ sumfix,
                                                     unsigned* __restrict__ ticket,
                                                     float* __restrict__ out) {
    int gm = blockIdx.x * TPB + threadIdx.x;
    int b = gm / NM, m = gm % NM;
    const float* sp = src + (size_t)b * 3 * NM;
    float x = sp[m], y = sp[NM + m], z = sp[2 * NM + m];
    float a2 = fmaf(x, x, fmaf(y, y, z * z));
    float v = dec_f32(minenc[gm]);
    float d = sqrtf(fmaxf(a2 + v, 0.0f));

    for (int off = 32; off > 0; off >>= 1) d += __shfl_down(d, off);
    __shared__ float wsum[4];
    int lane = threadIdx.x & 63, w = threadIdx.x >> 6;
    if (lane == 0) wsum[w] = d;
    __syncthreads();

    if (threadIdx.x == 0) {
        float bs = (wsum[0] + wsum[1]) + (wsum[2] + wsum[3]);
        // Fixed-point (32.32) accumulate: integer adds are associative ->
        // deterministic regardless of block order.
        unsigned long long inc = (unsigned long long)((double)bs * 4294967296.0);
        atomicAdd(sumfix, inc);
        __threadfence();                          // sum-add before ticket-add
        unsigned tk = atomicAdd(ticket, 1u);
        if (tk == NBLK_C - 1) {
            unsigned long long tot = atomicAdd(sumfix, 0ULL);  // coherent read
            out[0] = (float)((double)tot * (1.0 / 4294967296.0) * (1.0 / NPTS));
        }
    }
}

extern "C" void kernel_launch(void* const* d_in, const int* in_sizes, int n_in,
                              void* d_out, int out_size, void* d_ws, size_t ws_size,
                              hipStream_t stream) {
    const float* src = (const float*)d_in[0];   // [B,3,M]
    const float* dst = (const float*)d_in[1];   // [B,3,N]
    float* out = (float*)d_out;

    char* ws = (char*)d_ws;
    char* dstfrag = ws;                                              // 1 MB
    char* srcfrag = ws + (size_t)NPTS * 32;                          // 1 MB
    unsigned* minenc = (unsigned*)(ws + (size_t)NPTS * 64);          // 128 KB
    unsigned long long* sumfix =
        (unsigned long long*)(ws + (size_t)NPTS * 64 + (size_t)NPTS * 4);
    unsigned* ticket = (unsigned*)((char*)sumfix + 8);

    prep_kernel<<<NPTS / TPB, TPB, 0, stream>>>(src, dst, dstfrag, srcfrag,
                                                minenc, sumfix, ticket);
    minseg_kernel<<<NB * 64 * NSEG, TPB, 0, stream>>>(dstfrag, srcfrag, minenc);
    finish_kernel<<<NBLK_C, TPB, 0, stream>>>(src, minenc, sumfix, ticket, out);
}